// Round 16
// baseline (35.605 us; speedup 1.0000x reference)
//
#include <hip/hip_runtime.h>

// Direct-Form-II biquad over [B=64][T=262144]; independent blocks via warm-up
// truncation + XCD chunked swizzle + direct register loads (r15 base), now
// TWO consecutive tiles per block with exact continuation (B starts from
// A's end state) -- halves warm-up traffic and block count (one scheduling
// round) at unchanged occupancy (LDS = output transpose only, reused A->B).
//   v[t+1] = A v[t] + c x[t],  A = [[-a1,1],[-a2,0]],  c = [b1-a1*b0, b2-a2*b0]
//   out[t] = b0 x[t] + v0[t]

constexpr int BATCH = 64;
constexpr int T_LEN = 262144;
constexpr int TPB   = 256;            // threads per block
constexpr int LPT   = 32;             // samples per thread per tile
constexpr int TILE  = TPB * LPT;      // 8192 samples per tile
constexpr int SPAN  = 2 * TILE;       // 16384 samples per block
constexpr int NBPB  = T_LEN / SPAN;   // 16 blocks per batch chain
constexpr int NB    = BATCH * NBPB;   // 1024 blocks
constexpr int WUP   = 4096;           // warm-up samples (tile A only)
constexpr int NXCD  = 8;
constexpr int CPX   = NB / NXCD;      // 128 work-ids per XCD chunk

typedef float vfloat4 __attribute__((ext_vector_type(4)));

#define MATSQ(m00, m01, m10, m11)                                  \
    {                                                              \
        float n00 = fmaf(m00, m00, m01 * m10);                     \
        float n01 = fmaf(m00, m01, m01 * m11);                     \
        float n10 = fmaf(m10, m00, m11 * m10);                     \
        float n11 = fmaf(m10, m01, m11 * m11);                     \
        m00 = n00; m01 = n01; m10 = n10; m11 = n11;                \
    }

// composed 4-step update: v <- A^4 v + k3*xa + k2*xb + k1*xc + c*xd
#define CSTEP(p0, p1, xa, xb, xc, xd)                                        \
    {                                                                        \
        float n0 = fmaf(q00, p0, fmaf(q01, p1,                               \
                   fmaf(k3_0, (xa), fmaf(k2_0, (xb),                         \
                   fmaf(k1_0, (xc), c0 * (xd))))));                          \
        float n1 = fmaf(q10, p0, fmaf(q11, p1,                               \
                   fmaf(k3_1, (xa), fmaf(k2_1, (xb),                         \
                   fmaf(k1_1, (xc), c1 * (xd))))));                          \
        p0 = n0; p1 = n1;                                                    \
    }

__global__ __launch_bounds__(TPB, 4) void biquad_pair(
    const float* __restrict__ x, float* __restrict__ out,
    const float* __restrict__ pb0, const float* __restrict__ pb1,
    const float* __restrict__ pb2, const float* __restrict__ pa1,
    const float* __restrict__ pa2)
{
    __shared__ float lds[TPB][LPT + 1];   // output transpose buffer: 33,792 B
    __shared__ float swv[24];             // per wave w: [6w+0,1]=W [2,3]=A [4,5]=B

    const int tid  = threadIdx.x;
    const int lane = tid & 63;
    const int w    = tid >> 6;            // wave index 0..3

    // XCD-aware chunked swizzle (bijective: NB % 8 == 0)
    const int g    = (blockIdx.x & (NXCD - 1)) * CPX + (blockIdx.x >> 3);
    const int b    = g >> 4;              // batch
    const int k    = g & (NBPB - 1);      // pair position (16 per chain)

    const float b0 = *pb0, b1 = *pb1, b2 = *pb2;
    const float a1 = *pa1, a2 = *pa2;
    const float na1 = -a1, na2 = -a2;

    // ---- composed constants ----
    const float c0 = fmaf(na1, b0, b1), c1 = fmaf(na2, b0, b2);
    const float A00 = na1, A01 = 1.f, A10 = na2, A11 = 0.f;
    const float k1_0 = fmaf(A00, c0, A01 * c1);
    const float k1_1 = fmaf(A10, c0, A11 * c1);
    float B00 = A00, B01 = A01, B10 = A10, B11 = A11;
    MATSQ(B00, B01, B10, B11);                           // A^2
    const float k2_0 = fmaf(B00, c0, B01 * c1);
    const float k2_1 = fmaf(B10, c0, B11 * c1);
    const float k3_0 = fmaf(B00, k1_0, B01 * k1_1);
    const float k3_1 = fmaf(B10, k1_0, B11 * k1_1);
    float q00 = B00, q01 = B01, q10 = B10, q11 = B11;
    MATSQ(q00, q01, q10, q11);                           // A^4

    const size_t base = (size_t)b * T_LEN + (size_t)k * SPAN;

    // ---- issue ALL global loads up front (register-resident) ----
    float4 wq[4];
    if (k > 0) {
        const float4* wsrc =
            reinterpret_cast<const float4*>(x + base - WUP) + tid * 4;
#pragma unroll
        for (int i = 0; i < 4; ++i) wq[i] = wsrc[i];
    }
    const float4* xrowA = reinterpret_cast<const float4*>(x + base) + tid * (LPT / 4);
    const float4* xrowB = xrowA + TILE / 4;
    float4 xqA[8], xqB[8];
#pragma unroll
    for (int i = 0; i < 8; ++i) xqA[i] = xrowA[i];
#pragma unroll
    for (int i = 0; i < 8; ++i) xqB[i] = xrowB[i];

    // ---- pass 1: W (A^16), A (A^32), B (A^32) ----
    float pW0 = 0.f, pW1 = 0.f;
    if (k > 0) {
#pragma unroll
        for (int i = 0; i < 4; ++i)
            CSTEP(pW0, pW1, wq[i].x, wq[i].y, wq[i].z, wq[i].w);
    }
    float pA0 = 0.f, pA1 = 0.f;
#pragma unroll
    for (int i = 0; i < 8; ++i)
        CSTEP(pA0, pA1, xqA[i].x, xqA[i].y, xqA[i].z, xqA[i].w);
    float pB0 = 0.f, pB1 = 0.f;
#pragma unroll
    for (int i = 0; i < 8; ++i)
        CSTEP(pB0, pB1, xqB[i].x, xqB[i].y, xqB[i].z, xqB[i].w);

    // ---- chunk matrices: wa = A^16 track, m = A^32, wb = A^32 track ----
    float wa00 = q00, wa01 = q01, wa10 = q10, wa11 = q11;
    MATSQ(wa00, wa01, wa10, wa11);                       // A^8
    MATSQ(wa00, wa01, wa10, wa11);                       // A^16
    float m00 = wa00, m01 = wa01, m10 = wa10, m11 = wa11;
    MATSQ(m00, m01, m10, m11);                           // A^32
    float wb00 = m00, wb01 = m01, wb10 = m10, wb11 = m11;

    // ---- triple in-wave inclusive scan (two matrix tracks) ----
    for (int d = 1; d < 64; d <<= 1) {
        float oW0 = __shfl_up(pW0, d), oW1 = __shfl_up(pW1, d);
        float oA0 = __shfl_up(pA0, d), oA1 = __shfl_up(pA1, d);
        float oB0 = __shfl_up(pB0, d), oB1 = __shfl_up(pB1, d);
        if (lane >= d) {
            pW0 = fmaf(wa00, oW0, fmaf(wa01, oW1, pW0));
            pW1 = fmaf(wa10, oW0, fmaf(wa11, oW1, pW1));
            pA0 = fmaf(wb00, oA0, fmaf(wb01, oA1, pA0));
            pA1 = fmaf(wb10, oA0, fmaf(wb11, oA1, pA1));
            pB0 = fmaf(wb00, oB0, fmaf(wb01, oB1, pB0));
            pB1 = fmaf(wb10, oB0, fmaf(wb11, oB1, pB1));
        }
        MATSQ(wa00, wa01, wa10, wa11);
        MATSQ(wb00, wb01, wb10, wb11);
    }
    // post-scan: wa = A^1024 (QA), wb = A^2048 (QB)

    float einA0 = __shfl_up(pA0, 1), einA1 = __shfl_up(pA1, 1);
    float einB0 = __shfl_up(pB0, 1), einB1 = __shfl_up(pB1, 1);
    if (lane == 0) { einA0 = einA1 = einB0 = einB1 = 0.f; }

    if (lane == 63) {
        swv[6 * w]     = pW0; swv[6 * w + 1] = pW1;
        swv[6 * w + 2] = pA0; swv[6 * w + 3] = pA1;
        swv[6 * w + 4] = pB0; swv[6 * w + 5] = pB1;
    }
    __syncthreads();                                     // barrier #1

    // ---- Horner compositions ----
    // sA = warm-up total (tile-A start), QA spans 4 x 1024
    float sA0 = 0.f, sA1 = 0.f;
#pragma unroll
    for (int u = 0; u < 4; ++u) {
        float t0 = fmaf(wa00, sA0, fmaf(wa01, sA1, swv[6 * u]));
        float t1 = fmaf(wa10, sA0, fmaf(wa11, sA1, swv[6 * u + 1]));
        sA0 = t0; sA1 = t1;
    }
    // aggA = tile-A total (zero-init), QB spans 4 x 2048
    float agA0 = 0.f, agA1 = 0.f;
#pragma unroll
    for (int u = 0; u < 4; ++u) {
        float t0 = fmaf(wb00, agA0, fmaf(wb01, agA1, swv[6 * u + 2]));
        float t1 = fmaf(wb10, agA0, fmaf(wb11, agA1, swv[6 * u + 3]));
        agA0 = t0; agA1 = t1;
    }
    // cross-wave exclusive prefixes
    float cwA0 = 0.f, cwA1 = 0.f, cwB0 = 0.f, cwB1 = 0.f;
    for (int u = 0; u < w; ++u) {                         // <=3 iters
        float t0 = fmaf(wb00, cwA0, fmaf(wb01, cwA1, swv[6 * u + 2]));
        float t1 = fmaf(wb10, cwA0, fmaf(wb11, cwA1, swv[6 * u + 3]));
        cwA0 = t0; cwA1 = t1;
        float u0 = fmaf(wb00, cwB0, fmaf(wb01, cwB1, swv[6 * u + 4]));
        float u1 = fmaf(wb10, cwB0, fmaf(wb11, cwB1, swv[6 * u + 5]));
        cwB0 = u0; cwB1 = u1;
    }
    // sB = A^8192 * sA + aggA  (exact continuation); A^8192 = QB^4
    float P00 = wb00, P01 = wb01, P10 = wb10, P11 = wb11;
    MATSQ(P00, P01, P10, P11);
    MATSQ(P00, P01, P10, P11);                           // A^8192
    float sB0 = fmaf(P00, sA0, fmaf(P01, sA1, agA0));
    float sB1 = fmaf(P10, sA0, fmaf(P11, sA1, agA1));

    // ---- shared ladder (M = A^32): 4 vectors, one power track ----
    float vA0 = sA0, vA1 = sA1, vB0 = sB0, vB1 = sB1;
    float vcA0 = cwA0, vcA1 = cwA1, vcB0 = cwB0, vcB1 = cwB1;
    {
        float t00 = m00, t01 = m01, t10 = m10, t11 = m11;
#pragma unroll
        for (int bit = 0; bit < 8; ++bit) {
            if ((tid >> bit) & 1) {
                float n0, n1;
                n0 = fmaf(t00, vA0, t01 * vA1); n1 = fmaf(t10, vA0, t11 * vA1);
                vA0 = n0; vA1 = n1;
                n0 = fmaf(t00, vB0, t01 * vB1); n1 = fmaf(t10, vB0, t11 * vB1);
                vB0 = n0; vB1 = n1;
                if (bit < 6) {                   // lane bits == tid bits 0..5
                    n0 = fmaf(t00, vcA0, t01 * vcA1); n1 = fmaf(t10, vcA0, t11 * vcA1);
                    vcA0 = n0; vcA1 = n1;
                    n0 = fmaf(t00, vcB0, t01 * vcB1); n1 = fmaf(t10, vcB0, t11 * vcB1);
                    vcB0 = n0; vcB1 = n1;
                }
            }
            MATSQ(t00, t01, t10, t11);
        }
    }
    const float vAs0 = vA0 + vcA0 + einA0;
    const float vAs1 = vA1 + vcA1 + einA1;
    const float vBs0 = vB0 + vcB0 + einB0;
    const float vBs1 = vB1 + vcB1 + einB1;

    // ---- tile A: DF-I from registers -> LDS -> NT store ----
    {
        float xm2 = xqA[0].x, xm1 = xqA[0].y;
        float o2 = fmaf(xm2, b0, vAs0);
        float vn0 = fmaf(na1, o2, fmaf(xm2, b1, vAs1));
        float o1 = fmaf(xm1, b0, vn0);
        lds[tid][0] = o2; lds[tid][1] = o1;
#pragma unroll
        for (int t = 2; t < LPT; ++t) {
            float xt = (t & 3) == 0 ? xqA[t >> 2].x :
                       (t & 3) == 1 ? xqA[t >> 2].y :
                       (t & 3) == 2 ? xqA[t >> 2].z : xqA[t >> 2].w;
            float acc = fmaf(b1, xm1, fmaf(b2, xm2, na2 * o2));
            float o   = fmaf(b0, xt, fmaf(na1, o1, acc));
            lds[tid][t] = o;
            xm2 = xm1; xm1 = xt;
            o2 = o1; o1 = o;
        }
    }
    __syncthreads();                                     // barrier #2

    vfloat4* dstA = reinterpret_cast<vfloat4*>(out + base);
#pragma unroll
    for (int it = 0; it < 8; ++it) {
        int idx = it * TPB + tid;
        int e = idx * 4, c = e >> 5, t = e & 31;
        vfloat4 v;
        v.x = lds[c][t];     v.y = lds[c][t + 1];
        v.z = lds[c][t + 2]; v.w = lds[c][t + 3];
        __builtin_nontemporal_store(v, &dstA[idx]);
    }
    __syncthreads();                                     // barrier #3 (lds reuse)

    // ---- tile B: DF-I from registers -> LDS -> NT store ----
    {
        float xm2 = xqB[0].x, xm1 = xqB[0].y;
        float o2 = fmaf(xm2, b0, vBs0);
        float vn0 = fmaf(na1, o2, fmaf(xm2, b1, vBs1));
        float o1 = fmaf(xm1, b0, vn0);
        lds[tid][0] = o2; lds[tid][1] = o1;
#pragma unroll
        for (int t = 2; t < LPT; ++t) {
            float xt = (t & 3) == 0 ? xqB[t >> 2].x :
                       (t & 3) == 1 ? xqB[t >> 2].y :
                       (t & 3) == 2 ? xqB[t >> 2].z : xqB[t >> 2].w;
            float acc = fmaf(b1, xm1, fmaf(b2, xm2, na2 * o2));
            float o   = fmaf(b0, xt, fmaf(na1, o1, acc));
            lds[tid][t] = o;
            xm2 = xm1; xm1 = xt;
            o2 = o1; o1 = o;
        }
    }
    __syncthreads();                                     // barrier #4

    vfloat4* dstB = dstA + TILE / 4;
#pragma unroll
    for (int it = 0; it < 8; ++it) {
        int idx = it * TPB + tid;
        int e = idx * 4, c = e >> 5, t = e & 31;
        vfloat4 v;
        v.x = lds[c][t];     v.y = lds[c][t + 1];
        v.z = lds[c][t + 2]; v.w = lds[c][t + 3];
        __builtin_nontemporal_store(v, &dstB[idx]);
    }
}

extern "C" void kernel_launch(void* const* d_in, const int* in_sizes, int n_in,
                              void* d_out, int out_size, void* d_ws, size_t ws_size,
                              hipStream_t stream) {
    const float* x   = (const float*)d_in[0];
    const float* pb0 = (const float*)d_in[1];
    const float* pb1 = (const float*)d_in[2];
    const float* pb2 = (const float*)d_in[3];
    const float* pa1 = (const float*)d_in[4];
    const float* pa2 = (const float*)d_in[5];
    float* out = (float*)d_out;

    biquad_pair<<<NB, TPB, 0, stream>>>(x, out, pb0, pb1, pb2, pa1, pa2);
}

// Round 17
// 26.723 us; speedup vs baseline: 1.3324x; 1.3324x over previous
//
#include <hip/hip_runtime.h>

// Direct-Form-II biquad over [B=64][T=262144], fully independent blocks
// (warm-up truncation) + XCD-aware chunked swizzle + DIRECT per-thread
// global loads (no input LDS staging). LDS used only to transpose outputs
// for coalesced non-temporal stores. Measured optimum (r15: 26.7 us).
//   v[t+1] = A v[t] + c x[t],  A = [[-a1,1],[-a2,0]],  c = [b1-a1*b0, b2-a2*b0]
//   out[t] = b0 x[t] + v0[t]

constexpr int BATCH = 64;
constexpr int T_LEN = 262144;
constexpr int TPB   = 256;            // threads per block
constexpr int LPT   = 32;             // samples per thread (main tile)
constexpr int TILE  = TPB * LPT;      // 8192 samples per block
constexpr int NBPB  = T_LEN / TILE;   // 32 blocks per batch chain
constexpr int NB    = BATCH * NBPB;   // 2048 blocks
constexpr int WUP   = 4096;           // warm-up samples
constexpr int NXCD  = 8;
constexpr int CPX   = NB / NXCD;      // 256 work-ids per XCD chunk

typedef float vfloat4 __attribute__((ext_vector_type(4)));

#define MATSQ(m00, m01, m10, m11)                                  \
    {                                                              \
        float n00 = fmaf(m00, m00, m01 * m10);                     \
        float n01 = fmaf(m00, m01, m01 * m11);                     \
        float n10 = fmaf(m10, m00, m11 * m10);                     \
        float n11 = fmaf(m10, m01, m11 * m11);                     \
        m00 = n00; m01 = n01; m10 = n10; m11 = n11;                \
    }

// composed 4-step update: v <- A^4 v + k3*xa + k2*xb + k1*xc + c*xd
#define CSTEP(p0, p1, xa, xb, xc, xd)                                        \
    {                                                                        \
        float n0 = fmaf(q00, p0, fmaf(q01, p1,                               \
                   fmaf(k3_0, (xa), fmaf(k2_0, (xb),                         \
                   fmaf(k1_0, (xc), c0 * (xd))))));                          \
        float n1 = fmaf(q10, p0, fmaf(q11, p1,                               \
                   fmaf(k3_1, (xa), fmaf(k2_1, (xb),                         \
                   fmaf(k1_1, (xc), c1 * (xd))))));                          \
        p0 = n0; p1 = n1;                                                    \
    }

__global__ __launch_bounds__(TPB, 4) void biquad_direct(
    const float* __restrict__ x, float* __restrict__ out,
    const float* __restrict__ pb0, const float* __restrict__ pb1,
    const float* __restrict__ pb2, const float* __restrict__ pa1,
    const float* __restrict__ pa2)
{
    __shared__ float lds[TPB][LPT + 1];   // output transpose buffer: 33,792 B
    __shared__ float swv[16];             // wave aggregates: W pairs [0..7], B pairs [8..15]

    const int tid  = threadIdx.x;
    const int lane = tid & 63;
    const int w    = tid >> 6;            // wave index 0..3

    // XCD-aware chunked swizzle (bijective: NB % 8 == 0)
    const int g    = (blockIdx.x & (NXCD - 1)) * CPX + (blockIdx.x >> 3);
    const int b    = g >> 5;              // batch
    const int k    = g & (NBPB - 1);      // chain position

    const float b0 = *pb0, b1 = *pb1, b2 = *pb2;
    const float a1 = *pa1, a2 = *pa2;
    const float na1 = -a1, na2 = -a2;

    // ---- composed constants ----
    const float c0 = fmaf(na1, b0, b1), c1 = fmaf(na2, b0, b2);
    const float A00 = na1, A01 = 1.f, A10 = na2, A11 = 0.f;
    const float k1_0 = fmaf(A00, c0, A01 * c1);
    const float k1_1 = fmaf(A10, c0, A11 * c1);
    float B00 = A00, B01 = A01, B10 = A10, B11 = A11;
    MATSQ(B00, B01, B10, B11);                           // A^2
    const float k2_0 = fmaf(B00, c0, B01 * c1);
    const float k2_1 = fmaf(B10, c0, B11 * c1);
    const float k3_0 = fmaf(B00, k1_0, B01 * k1_1);
    const float k3_1 = fmaf(B10, k1_0, B11 * k1_1);
    float q00 = B00, q01 = B01, q10 = B10, q11 = B11;
    MATSQ(q00, q01, q10, q11);                           // A^4

    const size_t base = (size_t)b * T_LEN + (size_t)k * TILE;

    // ---- issue ALL global loads up front (no LDS staging) ----
    // main tile: thread's 32 contiguous samples = 8 x float4 (128-B lane stride)
    const float4* xrow = reinterpret_cast<const float4*>(x + base) + tid * (LPT / 4);
    float4 xq[8];
#pragma unroll
    for (int i = 0; i < 8; ++i) xq[i] = xrow[i];

    // warm-up: 16 preceding-region samples per thread (64-B lane stride)
    float4 wq[4];
    if (k > 0) {
        const float4* wsrc =
            reinterpret_cast<const float4*>(x + base - WUP) + tid * 4;
#pragma unroll
        for (int i = 0; i < 4; ++i) wq[i] = wsrc[i];
    }

    // ---- pass 1: warm-up carry (A^16) and main-tile carry (A^32) ----
    float pA0 = 0.f, pA1 = 0.f;
    if (k > 0) {
#pragma unroll
        for (int i = 0; i < 4; ++i)
            CSTEP(pA0, pA1, wq[i].x, wq[i].y, wq[i].z, wq[i].w);
    }
    float pB0 = 0.f, pB1 = 0.f;
#pragma unroll
    for (int i = 0; i < 8; ++i)
        CSTEP(pB0, pB1, xq[i].x, xq[i].y, xq[i].z, xq[i].w);

    // ---- chunk matrices: MA = A^16, MB = A^32 ----
    float wa00 = q00, wa01 = q01, wa10 = q10, wa11 = q11;
    MATSQ(wa00, wa01, wa10, wa11);                       // A^8
    MATSQ(wa00, wa01, wa10, wa11);                       // A^16
    float m00 = wa00, m01 = wa01, m10 = wa10, m11 = wa11;
    MATSQ(m00, m01, m10, m11);                           // A^32
    float wb00 = m00, wb01 = m01, wb10 = m10, wb11 = m11;

    // ---- dual in-wave inclusive scan (shfl only) ----
    for (int d = 1; d < 64; d <<= 1) {
        float oA0 = __shfl_up(pA0, d), oA1 = __shfl_up(pA1, d);
        float oB0 = __shfl_up(pB0, d), oB1 = __shfl_up(pB1, d);
        if (lane >= d) {
            pA0 = fmaf(wa00, oA0, fmaf(wa01, oA1, pA0));
            pA1 = fmaf(wa10, oA0, fmaf(wa11, oA1, pA1));
            pB0 = fmaf(wb00, oB0, fmaf(wb01, oB1, pB0));
            pB1 = fmaf(wb10, oB0, fmaf(wb11, oB1, pB1));
        }
        MATSQ(wa00, wa01, wa10, wa11);
        MATSQ(wb00, wb01, wb10, wb11);
    }
    // post-scan: wa = A^1024 (QA), wb = A^2048 (QB)

    // in-wave exclusive prefix for B
    float einB0 = __shfl_up(pB0, 1);
    float einB1 = __shfl_up(pB1, 1);
    if (lane == 0) { einB0 = 0.f; einB1 = 0.f; }

    if (lane == 63) {
        swv[2 * w] = pA0;     swv[2 * w + 1] = pA1;
        swv[8 + 2 * w] = pB0; swv[9 + 2 * w] = pB1;
    }
    __syncthreads();                                     // barrier #1

    // ---- sA = warm-up total (tile-start state), Horner with QA ----
    float sA0 = 0.f, sA1 = 0.f;
#pragma unroll
    for (int u = 0; u < 4; ++u) {
        float t0 = fmaf(wa00, sA0, fmaf(wa01, sA1, swv[2 * u]));
        float t1 = fmaf(wa10, sA0, fmaf(wa11, sA1, swv[2 * u + 1]));
        sA0 = t0; sA1 = t1;
    }
    // ---- cross-wave exclusive prefix for B, Horner with QB ----
    float cw0 = 0.f, cw1 = 0.f;
    for (int u = 0; u < w; ++u) {                         // <=3 iters
        float t0 = fmaf(wb00, cw0, fmaf(wb01, cw1, swv[8 + 2 * u]));
        float t1 = fmaf(wb10, cw0, fmaf(wb11, cw1, swv[9 + 2 * u]));
        cw0 = t0; cw1 = t1;
    }

    // ---- shared ladder: vs = M^tid * sA,  vc = M^lane * cw   (M = A^32) ----
    float vs0 = sA0, vs1 = sA1;
    float vc0 = cw0, vc1 = cw1;
    {
        float t00 = m00, t01 = m01, t10 = m10, t11 = m11;
#pragma unroll
        for (int bit = 0; bit < 8; ++bit) {
            if ((tid >> bit) & 1) {
                float n0 = fmaf(t00, vs0, t01 * vs1);
                float n1 = fmaf(t10, vs0, t11 * vs1);
                vs0 = n0; vs1 = n1;
                if (bit < 6) {                   // lane bits == tid bits 0..5
                    float u0 = fmaf(t00, vc0, t01 * vc1);
                    float u1 = fmaf(t10, vc0, t11 * vc1);
                    vc0 = u0; vc1 = u1;
                }
            }
            MATSQ(t00, t01, t10, t11);
        }
    }
    float v0 = vs0 + vc0 + einB0;
    float v1 = vs1 + vc1 + einB1;

    // ---- pass 2: Direct-Form-I from registers, outputs into LDS rows ----
    {
        float xm2 = xq[0].x, xm1 = xq[0].y;
        float o2 = fmaf(xm2, b0, v0);                     // out_0
        float vn0 = fmaf(na1, o2, fmaf(xm2, b1, v1));     // v0 at t=1
        float o1 = fmaf(xm1, b0, vn0);                    // out_1
        lds[tid][0] = o2; lds[tid][1] = o1;
#pragma unroll
        for (int t = 2; t < LPT; ++t) {
            float xt = (t & 3) == 0 ? xq[t >> 2].x :
                       (t & 3) == 1 ? xq[t >> 2].y :
                       (t & 3) == 2 ? xq[t >> 2].z : xq[t >> 2].w;
            float acc = fmaf(b1, xm1, fmaf(b2, xm2, na2 * o2));
            float o   = fmaf(b0, xt, fmaf(na1, o1, acc));
            lds[tid][t] = o;
            xm2 = xm1; xm1 = xt;
            o2 = o1; o1 = o;
        }
    }
    __syncthreads();                                     // barrier #2

    // ---- coalesced NON-TEMPORAL store ----
    vfloat4* dst = reinterpret_cast<vfloat4*>(out + base);
#pragma unroll
    for (int it = 0; it < 8; ++it) {
        int idx = it * TPB + tid;
        int e = idx * 4, c = e >> 5, t = e & 31;
        vfloat4 v;
        v.x = lds[c][t];     v.y = lds[c][t + 1];
        v.z = lds[c][t + 2]; v.w = lds[c][t + 3];
        __builtin_nontemporal_store(v, &dst[idx]);
    }
}

extern "C" void kernel_launch(void* const* d_in, const int* in_sizes, int n_in,
                              void* d_out, int out_size, void* d_ws, size_t ws_size,
                              hipStream_t stream) {
    const float* x   = (const float*)d_in[0];
    const float* pb0 = (const float*)d_in[1];
    const float* pb1 = (const float*)d_in[2];
    const float* pb2 = (const float*)d_in[3];
    const float* pa1 = (const float*)d_in[4];
    const float* pa2 = (const float*)d_in[5];
    float* out = (float*)d_out;

    biquad_direct<<<NB, TPB, 0, stream>>>(x, out, pb0, pb1, pb2, pa1, pa2);
}